// Round 7
// baseline (303.431 us; speedup 1.0000x reference)
//
#include <hip/hip_runtime.h>
#include <hip/hip_bf16.h>
#include <math.h>

typedef __bf16 bf16x4 __attribute__((ext_vector_type(4)));
typedef __bf16 bf16x8 __attribute__((ext_vector_type(8)));
typedef float  f32x4  __attribute__((ext_vector_type(4)));

#define BB 256
#define SS 1024
#define DD 128
#define HH 128
#define SDIM 5
#define LN_EPS 1e-5f
#define BST 136            // LDS weight row stride (elems): 272B, 2-way max (free)
#define C2T 2.8853900818f  // 2*log2(e)

// ---- fast accurate erf-gelu (A&S 7.1.26, |err| <= 1.5e-7) ----
__device__ __forceinline__ float gelu_erf_fast(float v){
    float x  = v * 0.70710678118654752f;
    float ax = fabsf(x);
    float t  = __builtin_amdgcn_rcpf(fmaf(0.3275911f, ax, 1.0f));
    float poly = t*(0.254829592f + t*(-0.284496736f + t*(1.421413741f +
                 t*(-1.453152027f + t*1.061405429f))));
    float e  = __builtin_amdgcn_exp2f(ax*ax * -1.4426950408889634f);
    float erfa = fmaf(-poly, e, 1.0f);
    float er = __builtin_copysignf(erfa, v);
    float hv = 0.5f * v;
    return fmaf(hv, er, hv);
}

// ---- cheap tanh-form gelu (|err|<=3e-3) for the correction path ----
__device__ __forceinline__ float gelu_fast(float x){
    float t = x*x;
    float u = x * fmaf(t, 0.044715f, 1.0f);
    float e = __builtin_amdgcn_exp2f(u * -2.3022080f);
    float rc = __builtin_amdgcn_rcpf(e + 1.0f);
    return x * rc;
}

__device__ __forceinline__ float tanh_fast(float x){
    float e = __builtin_amdgcn_exp2f(x * C2T);
    return fmaf(-2.0f, __builtin_amdgcn_rcpf(e + 1.0f), 1.0f);
}

__device__ __forceinline__ float sigm(float x){
    float e = __builtin_amdgcn_exp2f(-x * 1.4426950408889634f);
    return __builtin_amdgcn_rcpf(1.0f + e);
}

// permuted index: k' = r16*8 + f  <->  ktrue = (k'&7)*16 + (k'>>3)
__device__ __forceinline__ int ktrue(int kp){ return (kp & 7)*16 + (kp >> 3); }

// ---------- prep: weight layouts ----------
__global__ __launch_bounds__(128) void kprep(const float* __restrict__ W1,
        const float* __restrict__ Wc1, const float* __restrict__ Winn,
        const float* __restrict__ Wc2,
        __bf16* __restrict__ w1t, __bf16* __restrict__ wc1t,
        float* __restrict__ wcorr){
    int nb = blockIdx.x, k = threadIdx.x;
    if (nb < 128){
        w1t[nb*128 + k] = (__bf16)W1[k*128 + nb];
    } else if (nb < 272){
        int n = nb - 128;
        int kt = ktrue(k);
        float v;
        if (n < 128)      v = Wc1[(5 + kt)*128 + n];
        else if (n < 133) v = Winn[kt*5 + (n - 128)];
        else              v = 0.0f;
        wc1t[n*128 + k] = (__bf16)v;
    } else {
        int jt = ktrue(k);
        float* wp = wcorr + k*10;
#pragma unroll
        for (int s = 0; s < 5; s++) wp[s] = Wc1[s*128 + jt];
#pragma unroll
        for (int n = 0; n < 5; n++) wp[5+n] = Wc2[jt*5 + n];
    }
}

// ---------- pass 1: h = gelu(LN(x@W1+b1))  -> hmid bf16 [row][k'-packed] ----------
// 256 thr / 4 waves; 256 rows per block (4 iters of 64); x prefetched 1 iter ahead.
__global__ __launch_bounds__(256) void kg1(
        const float* __restrict__ x,
        const float* __restrict__ b1, const float* __restrict__ ln_g,
        const float* __restrict__ ln_b,
        const __bf16* __restrict__ w1t, __bf16* __restrict__ hmid)
{
    __shared__ __align__(16) __bf16 bw[128*BST];   // 34.8 KB
    const int t = threadIdx.x;
    const int w = t >> 6, l = t & 63;
    const int q = l >> 4, r16 = l & 15;
    const long m0 = (long)blockIdx.x * 256;

    // stage w1t -> LDS (padded rows), 8 x 16B per thread
#pragma unroll
    for (int i = 0; i < 8; i++){
        int g = t*16 + i*4096;
        int rr = g >> 8, col = (g & 255) >> 1;
        *(bf16x8*)&bw[rr*BST + col] = *(const bf16x8*)((const char*)w1t + g);
    }
    float b1c[8], lngc[8], lnbc[8];
#pragma unroll
    for (int f = 0; f < 8; f++){
        int c = f*16 + r16;
        b1c[f] = b1[c]; lngc[f] = ln_g[c]; lnbc[f] = ln_b[c];
    }
    // prefetch iteration 0's x
    float4 xf[8];
    {
        const float* xrow = x + (m0 + w*16 + r16)*128;
#pragma unroll
        for (int ks = 0; ks < 4; ks++){
            xf[2*ks]   = *(const float4*)(xrow + ks*32 + q*8);
            xf[2*ks+1] = *(const float4*)(xrow + ks*32 + q*8 + 4);
        }
    }
    __syncthreads();

    for (int it = 0; it < 4; it++){
        // convert prefetched x to A-frags
        bf16x8 af[4];
#pragma unroll
        for (int ks = 0; ks < 4; ks++){
            float4 v0 = xf[2*ks], v1 = xf[2*ks+1];
            bf16x8 a = { (__bf16)v0.x, (__bf16)v0.y, (__bf16)v0.z, (__bf16)v0.w,
                         (__bf16)v1.x, (__bf16)v1.y, (__bf16)v1.z, (__bf16)v1.w };
            af[ks] = a;
        }
        // issue next iteration's x loads (in flight under MFMA+epilogue)
        if (it < 3){
            const float* xrow = x + (m0 + (it+1)*64 + w*16 + r16)*128;
#pragma unroll
            for (int ks = 0; ks < 4; ks++){
                xf[2*ks]   = *(const float4*)(xrow + ks*32 + q*8);
                xf[2*ks+1] = *(const float4*)(xrow + ks*32 + q*8 + 4);
            }
        }
        f32x4 acc[8];
#pragma unroll
        for (int nf = 0; nf < 8; nf++){
            f32x4 c = {0.f, 0.f, 0.f, 0.f};
#pragma unroll
            for (int ks = 0; ks < 4; ks++){
                bf16x8 bfr = *(const bf16x8*)&bw[(nf*16 + r16)*BST + ks*32 + q*8];
                c = __builtin_amdgcn_mfma_f32_16x16x32_bf16(af[ks], bfr, c, 0, 0, 0);
            }
            acc[nf] = c;
        }
        // epilogue: +b1, LayerNorm, gelu, packed store
        float sum[4] = {0,0,0,0}, sq[4] = {0,0,0,0};
#pragma unroll
        for (int f = 0; f < 8; f++)
#pragma unroll
            for (int r = 0; r < 4; r++){
                float v = acc[f][r] + b1c[f];
                acc[f][r] = v; sum[r] += v; sq[r] += v*v;
            }
#pragma unroll
        for (int m = 1; m <= 8; m <<= 1){
#pragma unroll
            for (int r = 0; r < 4; r++){
                sum[r] += __shfl_xor(sum[r], m, 64);
                sq[r]  += __shfl_xor(sq[r],  m, 64);
            }
        }
#pragma unroll
        for (int r = 0; r < 4; r++){
            float mu = sum[r] * (1.0f/128.0f);
            float var = sq[r] * (1.0f/128.0f) - mu*mu;
            float rs = rsqrtf(var + LN_EPS);
            bf16x8 hp;
#pragma unroll
            for (int f = 0; f < 8; f++){
                float v = (acc[f][r] - mu) * rs * lngc[f] + lnbc[f];
                hp[f] = (__bf16)gelu_erf_fast(v);
            }
            *(bf16x8*)&hmid[(size_t)(m0 + it*64 + w*16 + q*4 + r)*128 + r16*8] = hp;
        }
    }
}

// ---------- pass 2: [Hc | bx] = h @ [Wc1' | Winn]  (k'-space both sides) ----------
// 256 rows per block; A-frags prefetched 1 iter ahead; Hc in place over hmid.
__global__ __launch_bounds__(256) void kg2(
        const __bf16* hmid,
        const __bf16* __restrict__ wc1t, const float* __restrict__ bc1,
        const float* __restrict__ binn,
        __bf16* Hc, float* __restrict__ bxo)
{
    __shared__ __align__(16) __bf16 bw[144*BST];   // 39.2 KB
    const int t = threadIdx.x;
    const int w = t >> 6, l = t & 63;
    const int q = l >> 4, r16 = l & 15;
    const long m0 = (long)blockIdx.x * 256;

    // stage wc1t -> LDS, 9 x 16B per thread
#pragma unroll
    for (int i = 0; i < 9; i++){
        int g = t*16 + i*4096;
        int rr = g >> 8, col = (g & 255) >> 1;
        *(bf16x8*)&bw[rr*BST + col] = *(const bf16x8*)((const char*)wc1t + g);
    }
    float bc1c[8];
#pragma unroll
    for (int f = 0; f < 8; f++) bc1c[f] = bc1[f*16 + r16];
    float bn = (r16 < 5) ? binn[r16] : 0.0f;
    // prefetch iteration 0's A-frags
    bf16x8 ha[4];
    {
        const __bf16* hrow = hmid + (size_t)(m0 + w*16 + r16)*128;
#pragma unroll
        for (int ks = 0; ks < 4; ks++)
            ha[ks] = *(const bf16x8*)(hrow + ks*32 + q*8);
    }
    __syncthreads();

    for (int it = 0; it < 4; it++){
        bf16x8 a2[4];
#pragma unroll
        for (int ks = 0; ks < 4; ks++) a2[ks] = ha[ks];
        if (it < 3){
            const __bf16* hrow = hmid + (size_t)(m0 + (it+1)*64 + w*16 + r16)*128;
#pragma unroll
            for (int ks = 0; ks < 4; ks++)
                ha[ks] = *(const bf16x8*)(hrow + ks*32 + q*8);
        }
        f32x4 acc2[9];
#pragma unroll
        for (int nf = 0; nf < 9; nf++){
            f32x4 c = {0.f,0.f,0.f,0.f};
#pragma unroll
            for (int ks = 0; ks < 4; ks++){
                bf16x8 bfr = *(const bf16x8*)&bw[(nf*16 + r16)*BST + ks*32 + q*8];
                c = __builtin_amdgcn_mfma_f32_16x16x32_bf16(a2[ks], bfr, c, 0, 0, 0);
            }
            acc2[nf] = c;
        }
#pragma unroll
        for (int r = 0; r < 4; r++){
            bf16x8 op;
#pragma unroll
            for (int nf = 0; nf < 8; nf++)
                op[nf] = (__bf16)(acc2[nf][r] + bc1c[nf]);
            *(bf16x8*)&Hc[(size_t)(m0 + it*64 + w*16 + q*4 + r)*128 + r16*8] = op;
        }
        if (r16 < 5){
#pragma unroll
            for (int r = 0; r < 4; r++)
                bxo[(size_t)(m0 + it*64 + w*16 + q*4 + r)*5 + r16] = acc2[8][r] + bn;
        }
    }
}

// ============ parallel affine scan machinery ============
struct ScanParams { float aL, aT, aR, wr, wi; };

__device__ __forceinline__ ScanParams load_params(
        const float* raL, const float* raT, const float* rg,
        const float* raR, const float* om){
    ScanParams p;
    p.aL = sigm(raL[0]) * 0.15f + 0.85f;
    p.aT = sigm(raT[0]) * 0.25f + 0.70f;
    float gq = sigm(rg[0]) * 0.20f + 0.80f;
    p.aR = sigm(raR[0]) * 0.40f;
    p.wr = cosf(om[0]) * gq;
    p.wi = -sinf(om[0]) * gq;
    return p;
}

// ---------- kscanlin: bx -> S_lin (full trajectory, uncorrected) ----------
__global__ __launch_bounds__(64) void kscanlin(
        const float* __restrict__ bx,
        const float* __restrict__ raw_aL, const float* __restrict__ raw_aT,
        const float* __restrict__ raw_g, const float* __restrict__ raw_aR,
        const float* __restrict__ omega, float* __restrict__ slin)
{
    const int b = blockIdx.x, l = threadIdx.x;
    ScanParams P = load_params(raw_aL, raw_aT, raw_g, raw_aR, omega);

    float4 uu[20];
    const float4* src = (const float4*)(bx + ((size_t)b*SS + l*16)*5);
#pragma unroll
    for (int i = 0; i < 20; i++) uu[i] = src[i];
    float* uf = (float*)uu;

    float cL=0.f, cT=0.f, c2r=0.f, c2i=0.f, cR=0.f;
#pragma unroll
    for (int i = 0; i < 16; i++){
        float u0=uf[i*5+0], u1=uf[i*5+1], u2=uf[i*5+2], u3=uf[i*5+3], u4=uf[i*5+4];
        cL = fmaf(P.aL, cL, u0);
        cT = fmaf(P.aT, cT, u1);
        float nr = fmaf(P.wr, c2r, fmaf(-P.wi, c2i, u2));
        float ni = fmaf(P.wr, c2i, fmaf( P.wi, c2r, u3));
        c2r = nr; c2i = ni;
        cR = fmaf(P.aR, cR, u4);
    }
    float mLa=P.aL, mTa=P.aT, mRa=P.aR, mwr=P.wr, mwi=P.wi;
#pragma unroll
    for (int i = 0; i < 4; i++){
        mLa *= mLa; mTa *= mTa; mRa *= mRa;
        float tr = mwr*mwr - mwi*mwi, ti = 2.f*mwr*mwi;
        mwr = tr; mwi = ti;
    }
#pragma unroll
    for (int d = 1; d < 64; d <<= 1){
        float pLa=__shfl_up(mLa,d), pLc=__shfl_up(cL,d);
        float pTa=__shfl_up(mTa,d), pTc=__shfl_up(cT,d);
        float pRa=__shfl_up(mRa,d), pRc=__shfl_up(cR,d);
        float pwr=__shfl_up(mwr,d), pwi=__shfl_up(mwi,d);
        float p2r=__shfl_up(c2r,d), p2i=__shfl_up(c2i,d);
        if (l >= d){
            cL = fmaf(mLa, pLc, cL); mLa *= pLa;
            cT = fmaf(mTa, pTc, cT); mTa *= pTa;
            cR = fmaf(mRa, pRc, cR); mRa *= pRa;
            float nr = fmaf(mwr, p2r, fmaf(-mwi, p2i, c2r));
            float ni = fmaf(mwr, p2i, fmaf( mwi, p2r, c2i));
            c2r = nr; c2i = ni;
            float twr = mwr*pwr - mwi*pwi, twi = mwr*pwi + mwi*pwr;
            mwr = twr; mwi = twi;
        }
    }
    float sL=__shfl_up(cL,1), sT=__shfl_up(cT,1), s2r=__shfl_up(c2r,1),
          s2i=__shfl_up(c2i,1), sR=__shfl_up(cR,1);
    if (l == 0){ sL=0.f; sT=0.f; s2r=0.f; s2i=0.f; sR=0.f; }
#pragma unroll
    for (int i = 0; i < 16; i++){
        float u0=uf[i*5+0], u1=uf[i*5+1], u2=uf[i*5+2], u3=uf[i*5+3], u4=uf[i*5+4];
        sL = fmaf(P.aL, sL, u0);
        sT = fmaf(P.aT, sT, u1);
        float nr = fmaf(P.wr, s2r, fmaf(-P.wi, s2i, u2));
        float ni = fmaf(P.wr, s2i, fmaf( P.wi, s2r, u3));
        s2r = nr; s2i = ni;
        sR = fmaf(P.aR, sR, u4);
        uf[i*5+0]=sL; uf[i*5+1]=sT; uf[i*5+2]=s2r; uf[i*5+3]=s2i; uf[i*5+4]=sR;
    }
    float4* dst = (float4*)(slin + ((size_t)b*SS + l*16)*5);
#pragma unroll
    for (int i = 0; i < 20; i++) dst[i] = uu[i];
}

// ---------- kcorr (coalesced + prefetch): u += cs*tanh(mlp(slin, Hc)) ----------
__global__ __launch_bounds__(256) void kcorr(
        const __bf16* __restrict__ Hc, const float* __restrict__ slin,
        const float* __restrict__ wcorr, const float* __restrict__ bc2,
        const float* __restrict__ corr_scale, float* __restrict__ u)
{
    const int t = threadIdx.x;
    const int w = t >> 6, l = t & 63;
    const int sl = l & 15, g = l >> 4;
    const size_t rbase = (size_t)blockIdx.x*256 + w*64;
    const float cs = corr_scale[0];

    // per-lane weights for j'' = sl*8 + jj  (80 fp32 regs)
    float W5[8][5], W2[8][5];
#pragma unroll
    for (int jj = 0; jj < 8; jj++){
        const float* wp = wcorr + (sl*8 + jj)*10;
        float2 a = *(const float2*)(wp+0);
        float2 b = *(const float2*)(wp+2);
        float2 c = *(const float2*)(wp+4);
        float2 d = *(const float2*)(wp+6);
        float2 e = *(const float2*)(wp+8);
        W5[jj][0]=a.x; W5[jj][1]=a.y; W5[jj][2]=b.x; W5[jj][3]=b.y; W5[jj][4]=c.x;
        W2[jj][0]=c.y; W2[jj][1]=d.x; W2[jj][2]=d.y; W2[jj][3]=e.x; W2[jj][4]=e.y;
    }
    float bb = (sl < 5) ? bc2[sl] : 0.0f;

    // prefetch iteration 0
    bf16x8 h8 = *(const bf16x8*)&Hc[(rbase + g)*128 + sl*8];
    const float* sp0 = slin + (rbase + g)*5;
    float s0=sp0[0], s1=sp0[1], s2=sp0[2], s3=sp0[3], s4=sp0[4];

    for (int it = 0; it < 16; it++){
        size_t r = rbase + it*4 + g;
        bf16x8 hc = h8;
        float t0=s0, t1=s1, t2=s2, t3=s3, t4=s4;
        if (it < 15){
            size_t rn = r + 4;
            h8 = *(const bf16x8*)&Hc[rn*128 + sl*8];
            const float* sp = slin + rn*5;
            s0=sp[0]; s1=sp[1]; s2=sp[2]; s3=sp[3]; s4=sp[4];
        }
        float o0=0.f,o1=0.f,o2=0.f,o3=0.f,o4=0.f;
#pragma unroll
        for (int jj = 0; jj < 8; jj++){
            float pre = (float)hc[jj];
            pre = fmaf(t0, W5[jj][0], fmaf(t1, W5[jj][1], fmaf(t2, W5[jj][2],
                  fmaf(t3, W5[jj][3], fmaf(t4, W5[jj][4], pre)))));
            float gg = gelu_fast(pre);
            o0 = fmaf(gg, W2[jj][0], o0);
            o1 = fmaf(gg, W2[jj][1], o1);
            o2 = fmaf(gg, W2[jj][2], o2);
            o3 = fmaf(gg, W2[jj][3], o3);
            o4 = fmaf(gg, W2[jj][4], o4);
        }
#pragma unroll
        for (int m = 1; m <= 8; m <<= 1){
            o0 += __shfl_xor(o0, m, 64);
            o1 += __shfl_xor(o1, m, 64);
            o2 += __shfl_xor(o2, m, 64);
            o3 += __shfl_xor(o3, m, 64);
            o4 += __shfl_xor(o4, m, 64);
        }
        if (sl < 5){
            float val = (sl==0) ? o0 : (sl==1) ? o1 : (sl==2) ? o2 :
                        (sl==3) ? o3 : o4;
            float* up = u + r*5 + sl;
            *up = *up + cs*tanh_fast(val + bb);
        }
    }
}

// ---------- kscanfin: u -> final state only ----------
__global__ __launch_bounds__(64) void kscanfin(
        const float* __restrict__ u,
        const float* __restrict__ raw_aL, const float* __restrict__ raw_aT,
        const float* __restrict__ raw_g, const float* __restrict__ raw_aR,
        const float* __restrict__ omega, float* __restrict__ out)
{
    const int b = blockIdx.x, l = threadIdx.x;
    ScanParams P = load_params(raw_aL, raw_aT, raw_g, raw_aR, omega);

    float4 uu[20];
    const float4* src = (const float4*)(u + ((size_t)b*SS + l*16)*5);
#pragma unroll
    for (int i = 0; i < 20; i++) uu[i] = src[i];
    float* uf = (float*)uu;

    float cL=0.f, cT=0.f, c2r=0.f, c2i=0.f, cR=0.f;
#pragma unroll
    for (int i = 0; i < 16; i++){
        float u0=uf[i*5+0], u1=uf[i*5+1], u2=uf[i*5+2], u3=uf[i*5+3], u4=uf[i*5+4];
        cL = fmaf(P.aL, cL, u0);
        cT = fmaf(P.aT, cT, u1);
        float nr = fmaf(P.wr, c2r, fmaf(-P.wi, c2i, u2));
        float ni = fmaf(P.wr, c2i, fmaf( P.wi, c2r, u3));
        c2r = nr; c2i = ni;
        cR = fmaf(P.aR, cR, u4);
    }
    float mLa=P.aL, mTa=P.aT, mRa=P.aR, mwr=P.wr, mwi=P.wi;
#pragma unroll
    for (int i = 0; i < 4; i++){
        mLa *= mLa; mTa *= mTa; mRa *= mRa;
        float tr = mwr*mwr - mwi*mwi, ti = 2.f*mwr*mwi;
        mwr = tr; mwi = ti;
    }
#pragma unroll
    for (int d = 1; d < 64; d <<= 1){
        float pLa=__shfl_up(mLa,d), pLc=__shfl_up(cL,d);
        float pTa=__shfl_up(mTa,d), pTc=__shfl_up(cT,d);
        float pRa=__shfl_up(mRa,d), pRc=__shfl_up(cR,d);
        float pwr=__shfl_up(mwr,d), pwi=__shfl_up(mwi,d);
        float p2r=__shfl_up(c2r,d), p2i=__shfl_up(c2i,d);
        if (l >= d){
            cL = fmaf(mLa, pLc, cL); mLa *= pLa;
            cT = fmaf(mTa, pTc, cT); mTa *= pTa;
            cR = fmaf(mRa, pRc, cR); mRa *= pRa;
            float nr = fmaf(mwr, p2r, fmaf(-mwi, p2i, c2r));
            float ni = fmaf(mwr, p2i, fmaf( mwi, p2r, c2i));
            c2r = nr; c2i = ni;
            float twr = mwr*pwr - mwi*pwi, twi = mwr*pwi + mwi*pwr;
            mwr = twr; mwi = twi;
        }
    }
    if (l == 63){
        out[b*5+0] = cL; out[b*5+1] = cT; out[b*5+2] = c2r;
        out[b*5+3] = c2i; out[b*5+4] = cR;
    }
}

extern "C" void kernel_launch(void* const* d_in, const int* in_sizes, int n_in,
                              void* d_out, int out_size, void* d_ws, size_t ws_size,
                              hipStream_t stream) {
    const float* x     = (const float*)d_in[0];
    const float* W1    = (const float*)d_in[1];
    const float* b1    = (const float*)d_in[2];
    const float* ln_g  = (const float*)d_in[3];
    const float* ln_b  = (const float*)d_in[4];
    const float* Winn  = (const float*)d_in[5];
    const float* binn  = (const float*)d_in[6];
    const float* Wc1   = (const float*)d_in[7];
    const float* bc1   = (const float*)d_in[8];
    const float* Wc2   = (const float*)d_in[9];
    const float* bc2   = (const float*)d_in[10];
    const float* corr  = (const float*)d_in[11];
    const float* raL   = (const float*)d_in[12];
    const float* raT   = (const float*)d_in[13];
    const float* rg    = (const float*)d_in[14];
    const float* raR   = (const float*)d_in[15];
    const float* om    = (const float*)d_in[16];

    char* ws = (char*)d_ws;
    __bf16* w1t   = (__bf16*)ws;                      // 32768 B        -> 32768
    __bf16* wc1t  = (__bf16*)(ws + 32768);            // 36864 B        -> 69632
    float*  wcorr = (float*)(ws + 69632);             // 5120 B         -> 74752
    __bf16* hmid  = (__bf16*)(ws + 74752);            // 64 MB          -> 67183616
    float*  bxb   = (float*)(ws + 67183616);          // 5 MB           -> 72426496
    float*  slin  = (float*)(ws + 72426496);          // 5 MB           -> 77669376

    kprep<<<dim3(273), dim3(128), 0, stream>>>(W1, Wc1, Winn, Wc2, w1t, wc1t, wcorr);
    kg1<<<dim3(1024), dim3(256), 0, stream>>>(x, b1, ln_g, ln_b, w1t, hmid);
    kg2<<<dim3(1024), dim3(256), 0, stream>>>(hmid, wc1t, bc1, binn,
                                              hmid /*in-place Hc*/, bxb);
    kscanlin<<<dim3(256), dim3(64), 0, stream>>>(bxb, raL, raT, rg, raR, om, slin);
    kcorr<<<dim3(1024), dim3(256), 0, stream>>>(hmid, slin, wcorr, bc2, corr, bxb);
    kscanfin<<<dim3(256), dim3(64), 0, stream>>>(bxb, raL, raT, rg, raR, om,
                                                 (float*)d_out);
}

// Round 9
// 280.407 us; speedup vs baseline: 1.0821x; 1.0821x over previous
//
#include <hip/hip_runtime.h>
#include <hip/hip_bf16.h>
#include <math.h>

typedef __bf16 bf16x4 __attribute__((ext_vector_type(4)));
typedef __bf16 bf16x8 __attribute__((ext_vector_type(8)));
typedef float  f32x4  __attribute__((ext_vector_type(4)));

#define BB 256
#define SS 1024
#define DD 128
#define HH 128
#define SDIM 5
#define LN_EPS 1e-5f
#define BST 136            // LDS row stride (elems): 272B, ~2-way max (free)
#define WEST 40            // LDS stride for extra-K block rows
#define C2T 2.8853900818f  // 2*log2(e)

// ---- fast accurate erf-gelu (A&S 7.1.26, |err| <= 1.5e-7) ----
__device__ __forceinline__ float gelu_erf_fast(float v){
    float x  = v * 0.70710678118654752f;
    float ax = fabsf(x);
    float t  = __builtin_amdgcn_rcpf(fmaf(0.3275911f, ax, 1.0f));
    float poly = t*(0.254829592f + t*(-0.284496736f + t*(1.421413741f +
                 t*(-1.453152027f + t*1.061405429f))));
    float e  = __builtin_amdgcn_exp2f(ax*ax * -1.4426950408889634f);
    float erfa = fmaf(-poly, e, 1.0f);
    float er = __builtin_copysignf(erfa, v);
    float hv = 0.5f * v;
    return fmaf(hv, er, hv);
}

// ---- cheap tanh-form gelu (|err|<=3e-3) for the correction path ----
__device__ __forceinline__ float gelu_fast(float x){
    float t = x*x;
    float u = x * fmaf(t, 0.044715f, 1.0f);
    float e = __builtin_amdgcn_exp2f(u * -2.3022080f);
    float rc = __builtin_amdgcn_rcpf(e + 1.0f);
    return x * rc;
}

__device__ __forceinline__ float tanh_fast(float x){
    float e = __builtin_amdgcn_exp2f(x * C2T);
    return fmaf(-2.0f, __builtin_amdgcn_rcpf(e + 1.0f), 1.0f);
}

__device__ __forceinline__ float sigm(float x){
    float e = __builtin_amdgcn_exp2f(-x * 1.4426950408889634f);
    return __builtin_amdgcn_rcpf(1.0f + e);
}

// permuted index: k' = r16*8 + f  <->  ktrue = (k'&7)*16 + (k'>>3)
__device__ __forceinline__ int ktrue(int kp){ return (kp & 7)*16 + (kp >> 3); }

// ---------- prep: weight layouts ----------
// blocks 0..127   : w1t[n][k]   (true k)       bf16
// blocks 128..271 : wc1t[n][k'] (permuted k)   bf16 (n<128: Wc1 h-part; 128..132 Winn; pad 0)
// block  272      : wce[n][k2]  extra-K block: Wc1 rows 0..4 (true order), 0-padded to 32
__global__ __launch_bounds__(128) void kprep(const float* __restrict__ W1,
        const float* __restrict__ Wc1, const float* __restrict__ Winn,
        __bf16* __restrict__ w1t, __bf16* __restrict__ wc1t,
        __bf16* __restrict__ wce){
    int nb = blockIdx.x, k = threadIdx.x;
    if (nb < 128){
        w1t[nb*128 + k] = (__bf16)W1[k*128 + nb];
    } else if (nb < 272){
        int n = nb - 128;
        int kt = ktrue(k);
        float v;
        if (n < 128)      v = Wc1[(5 + kt)*128 + n];
        else if (n < 133) v = Winn[kt*5 + (n - 128)];
        else              v = 0.0f;
        wc1t[n*128 + k] = (__bf16)v;
    } else {
        int n = k;  // 0..127
#pragma unroll
        for (int k2 = 0; k2 < 32; k2++)
            wce[n*32 + k2] = (k2 < 5) ? (__bf16)Wc1[k2*128 + n] : (__bf16)0.0f;
    }
}

// ---------- pass 1: h = gelu(LN(x@W1+b1)) -> hmid (k'-packed) ; bx = h@Winn+binn ----------
// 256 thr / 4 waves / 64 rows per block; bx via wave-private LDS round trip.
__global__ __launch_bounds__(256) void kg1(
        const float* __restrict__ x,
        const float* __restrict__ b1, const float* __restrict__ ln_g,
        const float* __restrict__ ln_b, const float* __restrict__ binn,
        const __bf16* __restrict__ w1t, const __bf16* __restrict__ wc1t,
        __bf16* __restrict__ hmid, float* __restrict__ bxo)
{
    __shared__ __align__(16) __bf16 bw[128*BST];   // 34.8 KB (W1 tile)
    __shared__ __align__(16) __bf16 hst[64*BST];   // 17.4 KB (h staging)
    const int t = threadIdx.x;
    const int w = t >> 6, l = t & 63;
    const int q = l >> 4, r16 = l & 15;
    const long m0 = (long)blockIdx.x * 64;
    const int row = w*16 + r16;

    // stage w1t -> LDS (padded rows), 8 x 16B per thread
#pragma unroll
    for (int i = 0; i < 8; i++){
        int g = t*16 + i*4096;
        int rr = g >> 8, col = (g & 255) >> 1;
        *(bf16x8*)&bw[rr*BST + col] = *(const bf16x8*)((const char*)w1t + g);
    }
    // A-frags straight from global x
    const float* xrow = x + (m0 + row)*128;
    bf16x8 af[4];
#pragma unroll
    for (int ks = 0; ks < 4; ks++){
        float4 v0 = *(const float4*)(xrow + ks*32 + q*8);
        float4 v1 = *(const float4*)(xrow + ks*32 + q*8 + 4);
        bf16x8 a = { (__bf16)v0.x, (__bf16)v0.y, (__bf16)v0.z, (__bf16)v0.w,
                     (__bf16)v1.x, (__bf16)v1.y, (__bf16)v1.z, (__bf16)v1.w };
        af[ks] = a;
    }
    float b1c[8], lngc[8], lnbc[8];
#pragma unroll
    for (int f = 0; f < 8; f++){
        int c = f*16 + r16;
        b1c[f] = b1[c]; lngc[f] = ln_g[c]; lnbc[f] = ln_b[c];
    }
    __syncthreads();

    f32x4 acc[8];
#pragma unroll
    for (int nf = 0; nf < 8; nf++){
        f32x4 c = {0.f, 0.f, 0.f, 0.f};
#pragma unroll
        for (int ks = 0; ks < 4; ks++){
            bf16x8 bfr = *(const bf16x8*)&bw[(nf*16 + r16)*BST + ks*32 + q*8];
            c = __builtin_amdgcn_mfma_f32_16x16x32_bf16(af[ks], bfr, c, 0, 0, 0);
        }
        acc[nf] = c;
    }
    // epilogue: +b1, LayerNorm, gelu; store hmid + hst (k'-packed)
    float sum[4] = {0,0,0,0}, sq[4] = {0,0,0,0};
#pragma unroll
    for (int f = 0; f < 8; f++)
#pragma unroll
        for (int r = 0; r < 4; r++){
            float v = acc[f][r] + b1c[f];
            acc[f][r] = v; sum[r] += v; sq[r] += v*v;
        }
#pragma unroll
    for (int m = 1; m <= 8; m <<= 1){
#pragma unroll
        for (int r = 0; r < 4; r++){
            sum[r] += __shfl_xor(sum[r], m, 64);
            sq[r]  += __shfl_xor(sq[r],  m, 64);
        }
    }
#pragma unroll
    for (int r = 0; r < 4; r++){
        float mu = sum[r] * (1.0f/128.0f);
        float var = sq[r] * (1.0f/128.0f) - mu*mu;
        float rs = rsqrtf(var + LN_EPS);
        bf16x8 hp;
#pragma unroll
        for (int f = 0; f < 8; f++){
            float v = (acc[f][r] - mu) * rs * lngc[f] + lnbc[f];
            hp[f] = (__bf16)gelu_erf_fast(v);
        }
        *(bf16x8*)&hmid[(size_t)(m0 + w*16 + q*4 + r)*128 + r16*8] = hp;
        *(bf16x8*)&hst[(w*16 + q*4 + r)*BST + r16*8] = hp;
    }
    // ---- bx = h @ Winn + binn  (wave-private LDS, no barrier needed) ----
    bf16x8 ab[4];
#pragma unroll
    for (int ks = 0; ks < 4; ks++)
        ab[ks] = *(const bf16x8*)&hst[row*BST + ks*32 + q*8];
    f32x4 cb = {0.f,0.f,0.f,0.f};
#pragma unroll
    for (int ks = 0; ks < 4; ks++){
        bf16x8 bwn = *(const bf16x8*)&wc1t[(128 + r16)*128 + ks*32 + q*8];
        cb = __builtin_amdgcn_mfma_f32_16x16x32_bf16(ab[ks], bwn, cb, 0, 0, 0);
    }
    if (r16 < 5){
        float bn = binn[r16];
#pragma unroll
        for (int r = 0; r < 4; r++)
            bxo[(size_t)(m0 + w*16 + q*4 + r)*5 + r16] = cb[r] + bn;
    }
}

// ============ parallel affine scan machinery ============
struct ScanParams { float aL, aT, aR, wr, wi; };

__device__ __forceinline__ ScanParams load_params(
        const float* raL, const float* raT, const float* rg,
        const float* raR, const float* om){
    ScanParams p;
    p.aL = sigm(raL[0]) * 0.15f + 0.85f;
    p.aT = sigm(raT[0]) * 0.25f + 0.70f;
    float gq = sigm(rg[0]) * 0.20f + 0.80f;
    p.aR = sigm(raR[0]) * 0.40f;
    p.wr = cosf(om[0]) * gq;
    p.wi = -sinf(om[0]) * gq;
    return p;
}

// ---------- kscanlin: bx -> S_lin (full trajectory, uncorrected) ----------
__global__ __launch_bounds__(64) void kscanlin(
        const float* __restrict__ bx,
        const float* __restrict__ raw_aL, const float* __restrict__ raw_aT,
        const float* __restrict__ raw_g, const float* __restrict__ raw_aR,
        const float* __restrict__ omega, float* __restrict__ slin)
{
    const int b = blockIdx.x, l = threadIdx.x;
    ScanParams P = load_params(raw_aL, raw_aT, raw_g, raw_aR, omega);

    float4 uu[20];
    const float4* src = (const float4*)(bx + ((size_t)b*SS + l*16)*5);
#pragma unroll
    for (int i = 0; i < 20; i++) uu[i] = src[i];
    float* uf = (float*)uu;

    float cL=0.f, cT=0.f, c2r=0.f, c2i=0.f, cR=0.f;
#pragma unroll
    for (int i = 0; i < 16; i++){
        float u0=uf[i*5+0], u1=uf[i*5+1], u2=uf[i*5+2], u3=uf[i*5+3], u4=uf[i*5+4];
        cL = fmaf(P.aL, cL, u0);
        cT = fmaf(P.aT, cT, u1);
        float nr = fmaf(P.wr, c2r, fmaf(-P.wi, c2i, u2));
        float ni = fmaf(P.wr, c2i, fmaf( P.wi, c2r, u3));
        c2r = nr; c2i = ni;
        cR = fmaf(P.aR, cR, u4);
    }
    float mLa=P.aL, mTa=P.aT, mRa=P.aR, mwr=P.wr, mwi=P.wi;
#pragma unroll
    for (int i = 0; i < 4; i++){
        mLa *= mLa; mTa *= mTa; mRa *= mRa;
        float tr = mwr*mwr - mwi*mwi, ti = 2.f*mwr*mwi;
        mwr = tr; mwi = ti;
    }
#pragma unroll
    for (int d = 1; d < 64; d <<= 1){
        float pLa=__shfl_up(mLa,d), pLc=__shfl_up(cL,d);
        float pTa=__shfl_up(mTa,d), pTc=__shfl_up(cT,d);
        float pRa=__shfl_up(mRa,d), pRc=__shfl_up(cR,d);
        float pwr=__shfl_up(mwr,d), pwi=__shfl_up(mwi,d);
        float p2r=__shfl_up(c2r,d), p2i=__shfl_up(c2i,d);
        if (l >= d){
            cL = fmaf(mLa, pLc, cL); mLa *= pLa;
            cT = fmaf(mTa, pTc, cT); mTa *= pTa;
            cR = fmaf(mRa, pRc, cR); mRa *= pRa;
            float nr = fmaf(mwr, p2r, fmaf(-mwi, p2i, c2r));
            float ni = fmaf(mwr, p2i, fmaf( mwi, p2r, c2i));
            c2r = nr; c2i = ni;
            float twr = mwr*pwr - mwi*pwi, twi = mwr*pwi + mwi*pwr;
            mwr = twr; mwi = twi;
        }
    }
    float sL=__shfl_up(cL,1), sT=__shfl_up(cT,1), s2r=__shfl_up(c2r,1),
          s2i=__shfl_up(c2i,1), sR=__shfl_up(cR,1);
    if (l == 0){ sL=0.f; sT=0.f; s2r=0.f; s2i=0.f; sR=0.f; }
#pragma unroll
    for (int i = 0; i < 16; i++){
        float u0=uf[i*5+0], u1=uf[i*5+1], u2=uf[i*5+2], u3=uf[i*5+3], u4=uf[i*5+4];
        sL = fmaf(P.aL, sL, u0);
        sT = fmaf(P.aT, sT, u1);
        float nr = fmaf(P.wr, s2r, fmaf(-P.wi, s2i, u2));
        float ni = fmaf(P.wr, s2i, fmaf( P.wi, s2r, u3));
        s2r = nr; s2i = ni;
        sR = fmaf(P.aR, sR, u4);
        uf[i*5+0]=sL; uf[i*5+1]=sT; uf[i*5+2]=s2r; uf[i*5+3]=s2i; uf[i*5+4]=sR;
    }
    float4* dst = (float4*)(slin + ((size_t)b*SS + l*16)*5);
#pragma unroll
    for (int i = 0; i < 20; i++) dst[i] = uu[i];
}

// ---------- kfuse: GEMM2 + correction, Hc never materialized ----------
// pre[r][j] = h[r]·Wc1'[:,j] (K=128, k'-space) + slin[r]·W5[:,j] (extra K-block) + bc1[j]
// u[r][n]  += cs * tanh( sum_j gelu(pre[r][j]) * Wc2[j][n] + bc2[n] )
__global__ __launch_bounds__(256) void kfuse(
        const __bf16* __restrict__ hmid, const float* __restrict__ slin,
        const __bf16* __restrict__ wc1t, const __bf16* __restrict__ wce,
        const float* __restrict__ bc1, const float* __restrict__ Wc2,
        const float* __restrict__ bc2, const float* __restrict__ corr_scale,
        float* __restrict__ u)
{
    __shared__ __align__(16) __bf16 bw[128*BST];   // 34.8 KB (Wc1' h-part)
    __shared__ __align__(16) __bf16 we[128*WEST];  // 10.2 KB (extra K-block)
    const int t = threadIdx.x;
    const int w = t >> 6, l = t & 63;
    const int q = l >> 4, r16 = l & 15;
    const long m0 = (long)blockIdx.x * 64;
    const int row = w*16 + r16;

    // stage wc1t rows 0..127 -> LDS
#pragma unroll
    for (int i = 0; i < 8; i++){
        int g = t*16 + i*4096;
        int rr = g >> 8, col = (g & 255) >> 1;
        *(bf16x8*)&bw[rr*BST + col] = *(const bf16x8*)((const char*)wc1t + g);
    }
    // stage wce (128x32) -> LDS stride 40
#pragma unroll
    for (int i = 0; i < 2; i++){
        int idx = t*8 + i*2048;            // element index
        int n = idx >> 5, c = idx & 31;
        *(bf16x8*)&we[n*WEST + c] = *(const bf16x8*)(wce + idx);
    }
    // A-frags from hmid (k'-packed)
    const __bf16* hrow = hmid + (size_t)(m0 + row)*128;
    bf16x8 a2[4];
#pragma unroll
    for (int ks = 0; ks < 4; ks++)
        a2[ks] = *(const bf16x8*)(hrow + ks*32 + q*8);
    // extra A-frag: q==0 lanes carry slin[row][0..4] as bf16, rest zero
    bf16x8 ae = { (__bf16)0.f,(__bf16)0.f,(__bf16)0.f,(__bf16)0.f,
                  (__bf16)0.f,(__bf16)0.f,(__bf16)0.f,(__bf16)0.f };
    if (q == 0){
        const float* sp = slin + (size_t)(m0 + row)*5;
        ae[0]=(__bf16)sp[0]; ae[1]=(__bf16)sp[1]; ae[2]=(__bf16)sp[2];
        ae[3]=(__bf16)sp[3]; ae[4]=(__bf16)sp[4];
    }
    // per-lane epilogue weights: true j = nf*16 + r16
    float bc1c[8], W2j[8][5];
#pragma unroll
    for (int nf = 0; nf < 8; nf++){
        int j = nf*16 + r16;
        bc1c[nf] = bc1[j];
        const float* wp = Wc2 + j*5;
#pragma unroll
        for (int n = 0; n < 5; n++) W2j[nf][n] = wp[n];
    }
    const float cs = corr_scale[0];
    float bb = (r16 < 5) ? bc2[r16] : 0.0f;
    __syncthreads();

    f32x4 acc2[8];
#pragma unroll
    for (int nf = 0; nf < 8; nf++){
        f32x4 c = {0.f,0.f,0.f,0.f};
#pragma unroll
        for (int ks = 0; ks < 4; ks++){
            bf16x8 bfr = *(const bf16x8*)&bw[(nf*16 + r16)*BST + ks*32 + q*8];
            c = __builtin_amdgcn_mfma_f32_16x16x32_bf16(a2[ks], bfr, c, 0, 0, 0);
        }
        bf16x8 bex = *(const bf16x8*)&we[(nf*16 + r16)*WEST + q*8];
        c = __builtin_amdgcn_mfma_f32_16x16x32_bf16(ae, bex, c, 0, 0, 0);
        acc2[nf] = c;
    }
    // correction epilogue: gelu + Wc2 reduce over j (8 regs x 16 lanes) + tanh
#pragma unroll
    for (int r = 0; r < 4; r++){
        float o0=0.f,o1=0.f,o2=0.f,o3=0.f,o4=0.f;
#pragma unroll
        for (int nf = 0; nf < 8; nf++){
            float gg = gelu_fast(acc2[nf][r] + bc1c[nf]);
            o0 = fmaf(gg, W2j[nf][0], o0);
            o1 = fmaf(gg, W2j[nf][1], o1);
            o2 = fmaf(gg, W2j[nf][2], o2);
            o3 = fmaf(gg, W2j[nf][3], o3);
            o4 = fmaf(gg, W2j[nf][4], o4);
        }
#pragma unroll
        for (int m = 1; m <= 8; m <<= 1){
            o0 += __shfl_xor(o0, m, 64);
            o1 += __shfl_xor(o1, m, 64);
            o2 += __shfl_xor(o2, m, 64);
            o3 += __shfl_xor(o3, m, 64);
            o4 += __shfl_xor(o4, m, 64);
        }
        if (r16 < 5){
            float val = (r16==0) ? o0 : (r16==1) ? o1 : (r16==2) ? o2 :
                        (r16==3) ? o3 : o4;
            float* up = u + (size_t)(m0 + w*16 + q*4 + r)*5 + r16;
            *up = *up + cs*tanh_fast(val + bb);
        }
    }
}

// ---------- kscanfin: u -> final state only ----------
__global__ __launch_bounds__(64) void kscanfin(
        const float* __restrict__ u,
        const float* __restrict__ raw_aL, const float* __restrict__ raw_aT,
        const float* __restrict__ raw_g, const float* __restrict__ raw_aR,
        const float* __restrict__ omega, float* __restrict__ out)
{
    const int b = blockIdx.x, l = threadIdx.x;
    ScanParams P = load_params(raw_aL, raw_aT, raw_g, raw_aR, omega);

    float4 uu[20];
    const float4* src = (const float4*)(u + ((size_t)b*SS + l*16)*5);
#pragma unroll
    for (int i = 0; i < 20; i++) uu[i] = src[i];
    float* uf = (float*)uu;

    float cL=0.f, cT=0.f, c2r=0.f, c2i=0.f, cR=0.f;
#pragma unroll
    for (int i = 0; i < 16; i++){
        float u0=uf[i*5+0], u1=uf[i*5+1], u2=uf[i*5+2], u3=uf[i*5+3], u4=uf[i*5+4];
        cL = fmaf(P.aL, cL, u0);
        cT = fmaf(P.aT, cT, u1);
        float nr = fmaf(P.wr, c2r, fmaf(-P.wi, c2i, u2));
        float ni = fmaf(P.wr, c2i, fmaf( P.wi, c2r, u3));
        c2r = nr; c2i = ni;
        cR = fmaf(P.aR, cR, u4);
    }
    float mLa=P.aL, mTa=P.aT, mRa=P.aR, mwr=P.wr, mwi=P.wi;
#pragma unroll
    for (int i = 0; i < 4; i++){
        mLa *= mLa; mTa *= mTa; mRa *= mRa;
        float tr = mwr*mwr - mwi*mwi, ti = 2.f*mwr*mwi;
        mwr = tr; mwi = ti;
    }
#pragma unroll
    for (int d = 1; d < 64; d <<= 1){
        float pLa=__shfl_up(mLa,d), pLc=__shfl_up(cL,d);
        float pTa=__shfl_up(mTa,d), pTc=__shfl_up(cT,d);
        float pRa=__shfl_up(mRa,d), pRc=__shfl_up(cR,d);
        float pwr=__shfl_up(mwr,d), pwi=__shfl_up(mwi,d);
        float p2r=__shfl_up(c2r,d), p2i=__shfl_up(c2i,d);
        if (l >= d){
            cL = fmaf(mLa, pLc, cL); mLa *= pLa;
            cT = fmaf(mTa, pTc, cT); mTa *= pTa;
            cR = fmaf(mRa, pRc, cR); mRa *= pRa;
            float nr = fmaf(mwr, p2r, fmaf(-mwi, p2i, c2r));
            float ni = fmaf(mwr, p2i, fmaf( mwi, p2r, c2i));
            c2r = nr; c2i = ni;
            float twr = mwr*pwr - mwi*pwi, twi = mwr*pwi + mwi*pwr;
            mwr = twr; mwi = twi;
        }
    }
    if (l == 63){
        out[b*5+0] = cL; out[b*5+1] = cT; out[b*5+2] = c2r;
        out[b*5+3] = c2i; out[b*5+4] = cR;
    }
}

extern "C" void kernel_launch(void* const* d_in, const int* in_sizes, int n_in,
                              void* d_out, int out_size, void* d_ws, size_t ws_size,
                              hipStream_t stream) {
    const float* x     = (const float*)d_in[0];
    const float* W1    = (const float*)d_in[1];
    const float* b1    = (const float*)d_in[2];
    const float* ln_g  = (const float*)d_in[3];
    const float* ln_b  = (const float*)d_in[4];
    const float* Winn  = (const float*)d_in[5];
    const float* binn  = (const float*)d_in[6];
    const float* Wc1   = (const float*)d_in[7];
    const float* bc1   = (const float*)d_in[8];
    const float* Wc2   = (const float*)d_in[9];
    const float* bc2   = (const float*)d_in[10];
    const float* corr  = (const float*)d_in[11];
    const float* raL   = (const float*)d_in[12];
    const float* raT   = (const float*)d_in[13];
    const float* rg    = (const float*)d_in[14];
    const float* raR   = (const float*)d_in[15];
    const float* om    = (const float*)d_in[16];

    char* ws = (char*)d_ws;
    __bf16* w1t   = (__bf16*)ws;                      // 32768 B  -> 32768
    __bf16* wc1t  = (__bf16*)(ws + 32768);            // 36864 B  -> 69632
    __bf16* wce   = (__bf16*)(ws + 69632);            // 8192 B   -> 77824
    __bf16* hmid  = (__bf16*)(ws + 77824);            // 64 MB    -> 67186688
    float*  bxb   = (float*)(ws + 67186688);          // 5 MB     -> 72429568
    float*  slin  = (float*)(ws + 72429568);          // 5 MB     -> 77672448

    kprep<<<dim3(273), dim3(128), 0, stream>>>(W1, Wc1, Winn, w1t, wc1t, wce);
    kg1<<<dim3(4096), dim3(256), 0, stream>>>(x, b1, ln_g, ln_b, binn,
                                              w1t, wc1t, hmid, bxb);
    kscanlin<<<dim3(256), dim3(64), 0, stream>>>(bxb, raL, raT, rg, raR, om, slin);
    kfuse<<<dim3(4096), dim3(256), 0, stream>>>(hmid, slin, wc1t, wce, bc1,
                                                Wc2, bc2, corr, bxb);
    kscanfin<<<dim3(256), dim3(64), 0, stream>>>(bxb, raL, raT, rg, raR, om,
                                                 (float*)d_out);
}